// Round 1
// baseline (812.944 us; speedup 1.0000x reference)
//
#include <hip/hip_runtime.h>
#include <stdint.h>
#include <math.h>

// Problem constants (Phi3 attention block)
#define B_   2
#define S_   2048
#define H_   3072
#define NH   32
#define NKV  8
#define HD   96
#define OPSZ 4608          // NH*HD + 2*NKV*HD
#define MM   (B_*S_)       // 4096 token rows

typedef __attribute__((ext_vector_type(8))) short short8;
typedef __attribute__((ext_vector_type(4))) float floatx4;

__device__ __forceinline__ short f2bf(float f) {
    union { float f; uint32_t u; } v; v.f = f;
    uint32_t r = v.u + 0x7fffu + ((v.u >> 16) & 1u);   // RNE
    return (short)(r >> 16);
}
__device__ __forceinline__ float bf2f(short s) {
    union { uint32_t u; float f; } v; v.u = ((uint32_t)(uint16_t)s) << 16;
    return v.f;
}

// ---------------------------------------------------------------- cast fp32->bf16
__global__ void cast_f32_bf16(const float* __restrict__ src, short* __restrict__ dst, int n4) {
    int i = blockIdx.x * blockDim.x + threadIdx.x;
    int stride = gridDim.x * blockDim.x;
    const float4* s4 = (const float4*)src;
    short4* d4 = (short4*)dst;
    for (; i < n4; i += stride) {
        float4 v = s4[i];
        short4 o;
        o.x = f2bf(v.x); o.y = f2bf(v.y); o.z = f2bf(v.z); o.w = f2bf(v.w);
        d4[i] = o;
    }
}

// ---------------------------------------------------------------- GEMM  C[M,N] = A[M,K] * B[N,K]^T   (bf16 in, fp32 acc)
// 128x128 tile, BK=32, 256 threads = 4 waves (2x2), each wave 64x64 via 4x4 MFMA 16x16x32.
template<int OUT_BF16>
__global__ __launch_bounds__(256) void gemm_bt(const short* __restrict__ A, const short* __restrict__ Bm,
                                               float* __restrict__ Cf, short* __restrict__ Cb,
                                               int M, int N, int K) {
    __shared__ short la[128 * 40];   // +8 pad: 80B row stride -> 2-way max conflicts
    __shared__ short lb[128 * 40];
    const int tid  = threadIdx.x;
    const int wave = tid >> 6, lane = tid & 63;
    const int L15  = lane & 15, quad = lane >> 4;
    const int m0 = blockIdx.y * 128, n0 = blockIdx.x * 128;
    const int wm = (wave >> 1) * 64, wn = (wave & 1) * 64;

    floatx4 acc[4][4];
    for (int i = 0; i < 4; i++)
        for (int j = 0; j < 4; j++)
            acc[i][j] = (floatx4){0.f, 0.f, 0.f, 0.f};

    for (int k0 = 0; k0 < K; k0 += 32) {
        __syncthreads();
        #pragma unroll
        for (int i = 0; i < 2; i++) {
            int c = tid + i * 256;          // 512 chunks of 8 bf16
            int row = c >> 2, col8 = c & 3;
            *(short8*)&la[row * 40 + col8 * 8] =
                *(const short8*)(A + (size_t)(m0 + row) * K + k0 + col8 * 8);
            *(short8*)&lb[row * 40 + col8 * 8] =
                *(const short8*)(Bm + (size_t)(n0 + row) * K + k0 + col8 * 8);
        }
        __syncthreads();
        short8 af[4], bfr[4];
        #pragma unroll
        for (int i = 0; i < 4; i++)
            af[i] = *(const short8*)&la[(wm + i * 16 + L15) * 40 + quad * 8];
        #pragma unroll
        for (int j = 0; j < 4; j++)
            bfr[j] = *(const short8*)&lb[(wn + j * 16 + L15) * 40 + quad * 8];
        #pragma unroll
        for (int i = 0; i < 4; i++)
            #pragma unroll
            for (int j = 0; j < 4; j++)
                acc[i][j] = __builtin_amdgcn_mfma_f32_16x16x32_bf16(af[i], bfr[j], acc[i][j], 0, 0, 0);
    }

    // C/D layout: col = lane&15, row = quad*4 + reg
    #pragma unroll
    for (int i = 0; i < 4; i++)
        #pragma unroll
        for (int j = 0; j < 4; j++)
            #pragma unroll
            for (int r = 0; r < 4; r++) {
                int row = m0 + wm + i * 16 + quad * 4 + r;
                int col = n0 + wn + j * 16 + L15;
                float v = acc[i][j][r];
                if (OUT_BF16) Cb[(size_t)row * N + col] = f2bf(v);
                else          Cf[(size_t)row * N + col] = v;
            }
}

// ---------------------------------------------------------------- RoPE + reorder q,k  (1/sqrt(hd) folded into Q)
__global__ void rope_reorder(const short* __restrict__ qkv, const int* __restrict__ pos_ids,
                             short* __restrict__ Q, short* __restrict__ Kc) {
    const int total = B_ * S_ * (NH + NKV) * HD;
    int idx = blockIdx.x * blockDim.x + threadIdx.x;
    int stride = gridDim.x * blockDim.x;
    for (; idx < total; idx += stride) {
        int d = idx % HD;
        int row = idx / HD;
        int h_all = row % (NH + NKV);
        int sb = row / (NH + NKV);
        int s = sb % S_;
        int b = sb / S_;
        int base = (b * S_ + s) * OPSZ;
        int off = (h_all < NH) ? (h_all * HD + d) : (H_ + (h_all - NH) * HD + d);
        float x = bf2f(qkv[base + off]);
        int delta = (d < 48) ? 48 : -48;
        float x2 = bf2f(qkv[base + off + delta]);
        int fi = d % 48;
        // inv_freq in double so phase error at pos~2047 stays ~1e-4 rad
        float inv = (float)exp((double)fi * -0.19188209098783242); // -ln(10000)/48
        float theta = (float)pos_ids[b * S_ + s] * inv;
        float sn, cs;
        sincosf(theta, &sn, &cs);
        float rot = (d < 48) ? -x2 : x2;
        float outv = x * cs + rot * sn;
        if (h_all < NH) {
            outv *= 0.10206207261596577f; // 1/sqrt(96)
            Q[((size_t)(b * NH + h_all) * S_ + s) * HD + d] = f2bf(outv);
        } else {
            Kc[((size_t)(b * NKV + (h_all - NH)) * S_ + s) * HD + d] = f2bf(outv);
        }
    }
}

// ---------------------------------------------------------------- V transpose: qkv[b,s,3840+kvh*96+d] -> Vt[b,kvh,d,s]
__global__ __launch_bounds__(256) void v_transpose(const short* __restrict__ qkv, short* __restrict__ Vt) {
    __shared__ short tile[64 * 104];
    int blk = blockIdx.x;
    int st  = blk & 31;
    int kvh = (blk >> 5) & 7;
    int b   = blk >> 8;
    int s0  = st * 64;
    int tid = threadIdx.x;
    #pragma unroll
    for (int i = 0; i < 3; i++) {
        int c = tid + i * 256;               // 64 rows x 12 chunks
        int row = c / 12, col8 = c % 12;
        *(short8*)&tile[row * 104 + col8 * 8] =
            *(const short8*)(qkv + (size_t)(b * S_ + s0 + row) * OPSZ + 3840 + kvh * HD + col8 * 8);
    }
    __syncthreads();
    #pragma unroll
    for (int i = 0; i < 3; i++) {
        int c = tid + i * 256;               // 96 rows x 8 chunks
        int d = c >> 3, col8 = c & 7;
        short8 v;
        #pragma unroll
        for (int j = 0; j < 8; j++) v[j] = tile[(col8 * 8 + j) * 104 + d];
        *(short8*)(Vt + ((size_t)(b * NKV + kvh) * HD + d) * S_ + s0 + col8 * 8) = v;
    }
}

// ---------------------------------------------------------------- causal flash attention, GQA 4:1
// block = (qt, h, b), 256 thr = 4 waves; wave owns 16 q rows; BQ=BKV=64.
__global__ __launch_bounds__(256) void flash_attn(const short* __restrict__ Q, const short* __restrict__ Kc,
                                                  const short* __restrict__ Vt, short* __restrict__ attn) {
    __shared__ short kl[64 * 104];       // K tile  [kv=64][hd=96] (+8 pad)
    __shared__ short vl[96 * 72];        // V tile  [hd=96][kv=64] (+8 pad)
    __shared__ short pl[4][16 * 72];     // P tile per wave [q=16][kv=64] (+8 pad)
    const int qt = blockIdx.x, h = blockIdx.y, b = blockIdx.z;
    const int kvh = h >> 2;
    const int q0 = qt * 64;
    const int tid = threadIdx.x, wave = tid >> 6, lane = tid & 63;
    const int L15 = lane & 15, quad = lane >> 4;

    short8 qf[3];
    {
        const short* qrow = Q + ((size_t)(b * NH + h) * S_ + q0 + wave * 16 + L15) * HD;
        #pragma unroll
        for (int kk = 0; kk < 3; kk++) qf[kk] = *(const short8*)(qrow + kk * 32 + quad * 8);
    }
    floatx4 o[6];
    #pragma unroll
    for (int nn = 0; nn < 6; nn++) o[nn] = (floatx4){0.f, 0.f, 0.f, 0.f};
    float m_r[4], l_r[4];
    #pragma unroll
    for (int r = 0; r < 4; r++) { m_r[r] = -3.0e38f; l_r[r] = 0.f; }

    for (int j = 0; j <= qt; j++) {
        const int kv0 = j * 64;
        __syncthreads();
        #pragma unroll
        for (int i = 0; i < 3; i++) {
            int c = tid + i * 256;
            int row = c / 12, col8 = c % 12;
            *(short8*)&kl[row * 104 + col8 * 8] =
                *(const short8*)(Kc + ((size_t)(b * NKV + kvh) * S_ + kv0 + row) * HD + col8 * 8);
            int vr = c >> 3, vc8 = c & 7;
            *(short8*)&vl[vr * 72 + vc8 * 8] =
                *(const short8*)(Vt + ((size_t)(b * NKV + kvh) * HD + vr) * S_ + kv0 + vc8 * 8);
        }
        __syncthreads();

        floatx4 sacc[4];
        #pragma unroll
        for (int n = 0; n < 4; n++) sacc[n] = (floatx4){0.f, 0.f, 0.f, 0.f};
        #pragma unroll
        for (int n = 0; n < 4; n++)
            #pragma unroll
            for (int kk = 0; kk < 3; kk++) {
                short8 kf = *(const short8*)&kl[(n * 16 + L15) * 104 + kk * 32 + quad * 8];
                sacc[n] = __builtin_amdgcn_mfma_f32_16x16x32_bf16(qf[kk], kf, sacc[n], 0, 0, 0);
            }

        if (j == qt) {  // diagonal tile: mask kv > q
            int qr_base = q0 + wave * 16 + quad * 4;
            #pragma unroll
            for (int n = 0; n < 4; n++) {
                int kv = kv0 + n * 16 + L15;
                #pragma unroll
                for (int r = 0; r < 4; r++)
                    if (kv > qr_base + r) sacc[n][r] = -3.0e38f;
            }
        }

        // online softmax; rows live in quads: row = quad*4 + reg, cols across L15 x 4 tiles
        float mx[4];
        #pragma unroll
        for (int r = 0; r < 4; r++)
            mx[r] = fmaxf(fmaxf(sacc[0][r], sacc[1][r]), fmaxf(sacc[2][r], sacc[3][r]));
        #pragma unroll
        for (int off = 1; off < 16; off <<= 1)
            #pragma unroll
            for (int r = 0; r < 4; r++) mx[r] = fmaxf(mx[r], __shfl_xor(mx[r], off));
        float alpha[4], rs[4];
        #pragma unroll
        for (int r = 0; r < 4; r++) {
            float mn = fmaxf(m_r[r], mx[r]);
            alpha[r] = __expf(m_r[r] - mn);
            m_r[r] = mn; rs[r] = 0.f;
        }
        #pragma unroll
        for (int n = 0; n < 4; n++)
            #pragma unroll
            for (int r = 0; r < 4; r++) {
                float p = __expf(sacc[n][r] - m_r[r]);
                sacc[n][r] = p; rs[r] += p;
            }
        #pragma unroll
        for (int off = 1; off < 16; off <<= 1)
            #pragma unroll
            for (int r = 0; r < 4; r++) rs[r] += __shfl_xor(rs[r], off);
        #pragma unroll
        for (int r = 0; r < 4; r++) l_r[r] = l_r[r] * alpha[r] + rs[r];
        #pragma unroll
        for (int nn = 0; nn < 6; nn++)
            #pragma unroll
            for (int r = 0; r < 4; r++) o[nn][r] *= alpha[r];

        // P (C-layout) -> LDS -> A-operand layout
        #pragma unroll
        for (int n = 0; n < 4; n++)
            #pragma unroll
            for (int r = 0; r < 4; r++)
                pl[wave][(quad * 4 + r) * 72 + n * 16 + L15] = f2bf(sacc[n][r]);
        __syncthreads();

        #pragma unroll
        for (int kk = 0; kk < 2; kk++) {
            short8 af = *(const short8*)&pl[wave][L15 * 72 + kk * 32 + quad * 8];
            #pragma unroll
            for (int nn = 0; nn < 6; nn++) {
                short8 vf = *(const short8*)&vl[(nn * 16 + L15) * 72 + kk * 32 + quad * 8];
                o[nn] = __builtin_amdgcn_mfma_f32_16x16x32_bf16(af, vf, o[nn], 0, 0, 0);
            }
        }
    }

    #pragma unroll
    for (int nn = 0; nn < 6; nn++)
        #pragma unroll
        for (int r = 0; r < 4; r++) {
            float v = o[nn][r] / l_r[r];
            int row = q0 + wave * 16 + quad * 4 + r;
            attn[((size_t)(b * S_) + row) * H_ + h * HD + nn * 16 + L15] = f2bf(v);
        }
}

// ---------------------------------------------------------------- launch
extern "C" void kernel_launch(void* const* d_in, const int* in_sizes, int n_in,
                              void* d_out, int out_size, void* d_ws, size_t ws_size,
                              hipStream_t stream) {
    const float* hid  = (const float*)d_in[0];
    const int*   pos  = (const int*)d_in[1];
    const float* wqkv = (const float*)d_in[2];
    const float* wo   = (const float*)d_in[3];
    float* out = (float*)d_out;
    char* ws = (char*)d_ws;

    // workspace layout (bytes) — total 173,015,040
    short* hid_b  = (short*)(ws + 0L);          // 4096*3072 bf16
    short* wqkv_b = (short*)(ws + 25165824L);   // 4608*3072 bf16
    short* wo_b   = (short*)(ws + 53477376L);   // 3072*3072 bf16
    short* qkv_b  = (short*)(ws + 72351744L);   // 4096*4608 bf16
    short* q_b    = (short*)(ws + 110100480L);  // [B,NH,S,HD] bf16
    short* k_b    = (short*)(ws + 135266304L);  // [B,NKV,S,HD] bf16
    short* vt_b   = (short*)(ws + 141557760L);  // [B,NKV,HD,S] bf16
    short* attn_b = (short*)(ws + 147849216L);  // [B,S,NH*HD] bf16

    cast_f32_bf16<<<4096, 256, 0, stream>>>(hid,  hid_b,  MM * H_ / 4);
    cast_f32_bf16<<<4096, 256, 0, stream>>>(wqkv, wqkv_b, OPSZ * H_ / 4);
    cast_f32_bf16<<<4096, 256, 0, stream>>>(wo,   wo_b,   H_ * H_ / 4);

    gemm_bt<1><<<dim3(OPSZ / 128, MM / 128), 256, 0, stream>>>(hid_b, wqkv_b, nullptr, qkv_b, MM, OPSZ, H_);

    rope_reorder<<<8192, 256, 0, stream>>>(qkv_b, pos, q_b, k_b);
    v_transpose<<<512, 256, 0, stream>>>(qkv_b, vt_b);

    flash_attn<<<dim3(S_ / 64, NH, B_), 256, 0, stream>>>(q_b, k_b, vt_b, attn_b);

    gemm_bt<0><<<dim3(H_ / 128, MM / 128), 256, 0, stream>>>(attn_b, wo_b, out, nullptr, MM, H_, H_);
}